// Round 2
// baseline (389.536 us; speedup 1.0000x reference)
//
#include <hip/hip_runtime.h>
#include <hip/hip_bf16.h>

typedef __bf16 bf16_8 __attribute__((ext_vector_type(8)));
typedef float f32x4 __attribute__((ext_vector_type(4)));

#define NNODES 113
#define NGRAPH 4096

// ---------------- ws layout (bytes) ----------------
#define Z_OFF    0u            // 4096*128*4   = 2,097,152
#define P_OFF    2097152u      // 4096*512*4   = 8,388,608
#define SSUM_OFF 10485760u     // 512*4
#define SSQ_OFF  10487808u     // 512*4
#define SA_OFF   10489856u     // 512*4
#define SD_OFF   10491904u     // 512*4
#define W2H_OFF  10493952u     // 16384*2
#define W2L_OFF  10526720u     // 16384*2
#define W4P_OFF  10559488u     // 524288*2  -> end 11,608,064

// K0: pack W2 (hi+lo split) / W4 to bf16 B-fragment layout; zero BN accumulators.
// B-frag layout: elem ((kt*NT + nt)*64 + lane)*8 + j  <=  W[k][n],
//   k = kt*32 + (lane>>4)*8 + j, n = nt*16 + (lane&15)
__global__ __launch_bounds__(256) void k0_prep(
    const float* __restrict__ W2, const float* __restrict__ W4,
    __bf16* __restrict__ w2h, __bf16* __restrict__ w2l,
    __bf16* __restrict__ w4p,
    float* __restrict__ stats /*1024 floats: ssum|ssq*/) {
  int i = blockIdx.x * 256 + threadIdx.x;
  if (i < 524288) {                       // W4: NT=64 (N=1024), KT=16 (K=512)
    int j = i & 7, L = (i >> 3) & 63, nt = (i >> 9) & 63, kt = i >> 15;
    int k = kt * 32 + ((L >> 4) << 3) + j;
    int n = (nt << 4) + (L & 15);
    w4p[i] = (__bf16)W4[k * 1024 + n];
  } else if (i < 524288 + 16384) {        // W2: NT=8 (N=128), KT=4 (K=128), hi+lo
    int q = i - 524288;
    int j = q & 7, L = (q >> 3) & 63, nt = (q >> 9) & 7, kt = q >> 12;
    int k = kt * 32 + ((L >> 4) << 3) + j;
    int n = (nt << 4) + (L & 15);
    float v = W2[k * 128 + n];
    __bf16 h = (__bf16)v;
    w2h[q] = h;
    w2l[q] = (__bf16)(v - (float)h);
  } else if (i < 524288 + 16384 + 1024) {
    stats[i - (524288 + 16384)] = 0.0f;
  }
}

// K1: per-graph node net + max pool. 1 block = 1 graph, 256 threads.
// GEMM in split-bf16 (3-pass compensated MFMA) => fp32-quality z.
__global__ __launch_bounds__(256) void k1_nodenet(
    const float* __restrict__ x, const float* __restrict__ roi,
    const float* __restrict__ W1, const float* __restrict__ b1,
    const float* __restrict__ gn_g, const float* __restrict__ gn_b,
    const __bf16* __restrict__ w2h, const __bf16* __restrict__ w2l,
    const float* __restrict__ b2, float* __restrict__ z) {
  __shared__ float xs[NNODES * 3 + 1];
  __shared__ __bf16 Ah[128 * 136];  // pitch 136 bf16 (2-way bank alias = free)
  __shared__ __bf16 Al[128 * 136];
  int t = threadIdx.x, g = blockIdx.x;

  for (int i = t; i < NNODES * 3; i += 256)
    xs[i] = x[g * (NNODES * 3) + i] * roi[i];

  int c = t & 127, half = t >> 7;
  float w0 = W1[c], w1 = W1[128 + c], w2 = W1[256 + c];
  float b1c = b1[c], gg = gn_g[c], gb = gn_b[c];
  __syncthreads();

  // Phase A: h1 -> GroupNorm(16ch groups == 16 aligned lanes) -> leaky -> split bf16 LDS
  for (int n = half; n < 128; n += 2) {
    float y;
    if (n < NNODES) {
      float h = fmaf(xs[n * 3 + 2], w2, fmaf(xs[n * 3 + 1], w1, fmaf(xs[n * 3], w0, b1c)));
      float s = h, q = h * h;
#pragma unroll
      for (int m = 1; m < 16; m <<= 1) {
        s += __shfl_xor(s, m, 64);
        q += __shfl_xor(q, m, 64);
      }
      float mu = s * 0.0625f;
      float var = fmaxf(q * 0.0625f - mu * mu, 0.0f);
      float hn = (h - mu) * rsqrtf(var + 1e-5f);
      y = hn * gg + gb;
      y = (y > 0.0f) ? y : 0.2f * y;
    } else {
      y = 0.0f;  // pad rows 113..127
    }
    __bf16 yh = (__bf16)y;
    Ah[n * 136 + c] = yh;
    Al[n * 136 + c] = (__bf16)(y - (float)yh);
  }
  __syncthreads();

  // Phase B: [128x128] @ W2[128x128] via mfma 16x16x32; wave w owns n-tiles {2w,2w+1}
  int lane = t & 63, wv = t >> 6;
  int quad = lane >> 4, l16 = lane & 15;
  f32x4 acc[2][8];
#pragma unroll
  for (int a = 0; a < 2; a++)
#pragma unroll
    for (int m = 0; m < 8; m++) acc[a][m] = (f32x4){0.f, 0.f, 0.f, 0.f};

#pragma unroll
  for (int kt = 0; kt < 4; kt++) {
    bf16_8 ah[8], al[8];
#pragma unroll
    for (int mt = 0; mt < 8; mt++) {
      int off = (mt * 16 + l16) * 136 + kt * 32 + quad * 8;
      ah[mt] = *(const bf16_8*)&Ah[off];
      al[mt] = *(const bf16_8*)&Al[off];
    }
#pragma unroll
    for (int ni = 0; ni < 2; ni++) {
      int nt = wv * 2 + ni;
      int boff = ((kt * 8 + nt) * 64 + lane) * 8;
      bf16_8 bh = *(const bf16_8*)&w2h[boff];
      bf16_8 bl = *(const bf16_8*)&w2l[boff];
#pragma unroll
      for (int mt = 0; mt < 8; mt++) {
        acc[ni][mt] = __builtin_amdgcn_mfma_f32_16x16x32_bf16(ah[mt], bh, acc[ni][mt], 0, 0, 0);
        acc[ni][mt] = __builtin_amdgcn_mfma_f32_16x16x32_bf16(al[mt], bh, acc[ni][mt], 0, 0, 0);
        acc[ni][mt] = __builtin_amdgcn_mfma_f32_16x16x32_bf16(ah[mt], bl, acc[ni][mt], 0, 0, 0);
      }
    }
  }

  // Column max over valid rows (C layout: row = quad*4+r, col = lane&15), + b2
#pragma unroll
  for (int ni = 0; ni < 2; ni++) {
    int nt = wv * 2 + ni;
    float m = -3.4e38f;
#pragma unroll
    for (int mt = 0; mt < 8; mt++) {
#pragma unroll
      for (int r = 0; r < 4; r++) {
        int row = mt * 16 + quad * 4 + r;
        if (row < NNODES) m = fmaxf(m, acc[ni][mt][r]);
      }
    }
    m = fmaxf(m, __shfl_xor(m, 16, 64));
    m = fmaxf(m, __shfl_xor(m, 32, 64));
    if (quad == 0) {
      int col = nt * 16 + l16;
      z[g * 128 + col] = m + b2[col];
    }
  }
}

// K2: p = z @ W3 + b3 (fp32), 16 rows/block; BN partial sums -> atomics
__global__ __launch_bounds__(256) void k2_proj(
    const float* __restrict__ z, const float* __restrict__ W3,
    const float* __restrict__ b3, float* __restrict__ p,
    float* __restrict__ ssum, float* __restrict__ ssq) {
  __shared__ float zs[16 * 128];
  __shared__ float red[4 * 512];
  int t = threadIdx.x;
  int gr0 = blockIdx.x * 16;
  for (int i = t; i < 2048; i += 256) zs[i] = z[gr0 * 128 + i];
  int wv = t >> 6;
  int r0 = wv * 4;
  int c0 = (t & 63) * 8;
  float bb[8];
#pragma unroll
  for (int b = 0; b < 8; b++) bb[b] = b3[c0 + b];
  float acc[4][8];
#pragma unroll
  for (int a = 0; a < 4; a++)
#pragma unroll
    for (int b = 0; b < 8; b++) acc[a][b] = 0.0f;
  __syncthreads();

  for (int k = 0; k < 128; k++) {
    float4 wA = *(const float4*)&W3[k * 512 + c0];
    float4 wB = *(const float4*)&W3[k * 512 + c0 + 4];
#pragma unroll
    for (int a = 0; a < 4; a++) {
      float zv = zs[(r0 + a) * 128 + k];
      acc[a][0] = fmaf(zv, wA.x, acc[a][0]);
      acc[a][1] = fmaf(zv, wA.y, acc[a][1]);
      acc[a][2] = fmaf(zv, wA.z, acc[a][2]);
      acc[a][3] = fmaf(zv, wA.w, acc[a][3]);
      acc[a][4] = fmaf(zv, wB.x, acc[a][4]);
      acc[a][5] = fmaf(zv, wB.y, acc[a][5]);
      acc[a][6] = fmaf(zv, wB.z, acc[a][6]);
      acc[a][7] = fmaf(zv, wB.w, acc[a][7]);
    }
  }

  float csum[8], csq[8];
#pragma unroll
  for (int b = 0; b < 8; b++) { csum[b] = 0.0f; csq[b] = 0.0f; }
#pragma unroll
  for (int a = 0; a < 4; a++) {
    int row = gr0 + r0 + a;
#pragma unroll
    for (int b = 0; b < 8; b++) {
      float v = acc[a][b] + bb[b];
      acc[a][b] = v;
      csum[b] += v;
      csq[b] += v * v;
    }
    float4 o0 = make_float4(acc[a][0], acc[a][1], acc[a][2], acc[a][3]);
    float4 o1 = make_float4(acc[a][4], acc[a][5], acc[a][6], acc[a][7]);
    *(float4*)&p[row * 512 + c0] = o0;
    *(float4*)&p[row * 512 + c0 + 4] = o1;
  }
#pragma unroll
  for (int b = 0; b < 8; b++) red[wv * 512 + c0 + b] = csum[b];
  __syncthreads();
  for (int ch = t; ch < 512; ch += 256)
    atomicAdd(&ssum[ch], red[ch] + red[512 + ch] + red[1024 + ch] + red[1536 + ch]);
  __syncthreads();
#pragma unroll
  for (int b = 0; b < 8; b++) red[wv * 512 + c0 + b] = csq[b];
  __syncthreads();
  for (int ch = t; ch < 512; ch += 256)
    atomicAdd(&ssq[ch], red[ch] + red[512 + ch] + red[1024 + ch] + red[1536 + ch]);
}

// K3: finalize BN -> per-channel scale a, shift d
__global__ __launch_bounds__(512) void k3_stats(
    const float* __restrict__ ssum, const float* __restrict__ ssq,
    const float* __restrict__ bn_g, const float* __restrict__ bn_b,
    float* __restrict__ sa, float* __restrict__ sd) {
  int c = threadIdx.x;
  float mu = ssum[c] * (1.0f / 4096.0f);
  float var = fmaxf(ssq[c] * (1.0f / 4096.0f) - mu * mu, 0.0f);
  float s = bn_g[c] * rsqrtf(var + 1e-5f);
  sa[c] = s;
  sd[c] = bn_b[c] - mu * s;
}

// K4: out = L2norm( relu(p*a+d) @ W4 + b4 ), 16 rows/block via MFMA
__global__ __launch_bounds__(256) void k4_final(
    const float* __restrict__ p, const float* __restrict__ sa,
    const float* __restrict__ sd, const __bf16* __restrict__ w4p,
    const float* __restrict__ b4, float* __restrict__ out) {
  __shared__ __bf16 As[16 * 520];
  __shared__ float rred[4 * 16];
  int t = threadIdx.x;
  int gr0 = blockIdx.x * 16;

  for (int i = t; i < 16 * 512; i += 256) {
    int row = i >> 9, col = i & 511;
    float v = fmaf(p[gr0 * 512 + i], sa[col], sd[col]);
    v = fmaxf(v, 0.0f);
    As[row * 520 + col] = (__bf16)v;
  }
  __syncthreads();

  int lane = t & 63, wv = t >> 6, quad = lane >> 4, l16 = lane & 15;
  f32x4 acc[16];
#pragma unroll
  for (int ni = 0; ni < 16; ni++) acc[ni] = (f32x4){0.f, 0.f, 0.f, 0.f};

  for (int kt = 0; kt < 16; kt++) {
    bf16_8 afr = *(const bf16_8*)&As[l16 * 520 + kt * 32 + quad * 8];
#pragma unroll
    for (int ni = 0; ni < 16; ni++) {
      int nt = wv * 16 + ni;
      bf16_8 bfr = *(const bf16_8*)&w4p[((kt * 64 + nt) * 64 + lane) * 8];
      acc[ni] = __builtin_amdgcn_mfma_f32_16x16x32_bf16(afr, bfr, acc[ni], 0, 0, 0);
    }
  }

  // +b4, per-row sumsq: reduce over 16 lanes (cols) then across waves via LDS
  float rs[4] = {0.f, 0.f, 0.f, 0.f};
#pragma unroll
  for (int ni = 0; ni < 16; ni++) {
    int col = (wv * 16 + ni) * 16 + l16;
    float bv = b4[col];
#pragma unroll
    for (int r = 0; r < 4; r++) {
      float v = acc[ni][r] + bv;
      acc[ni][r] = v;
      rs[r] += v * v;
    }
  }
#pragma unroll
  for (int m = 1; m < 16; m <<= 1) {
#pragma unroll
    for (int r = 0; r < 4; r++) rs[r] += __shfl_xor(rs[r], m, 64);
  }
  if (l16 == 0) {
#pragma unroll
    for (int r = 0; r < 4; r++) rred[wv * 16 + quad * 4 + r] = rs[r];
  }
  __syncthreads();

  float inv[4];
#pragma unroll
  for (int r = 0; r < 4; r++) {
    int row = quad * 4 + r;
    float s = rred[row] + rred[16 + row] + rred[32 + row] + rred[48 + row];
    inv[r] = 1.0f / fmaxf(sqrtf(s), 1e-12f);
  }
#pragma unroll
  for (int ni = 0; ni < 16; ni++) {
    int col = (wv * 16 + ni) * 16 + l16;
#pragma unroll
    for (int r = 0; r < 4; r++) {
      int row = gr0 + quad * 4 + r;
      out[row * 1024 + col] = acc[ni][r] * inv[r];
    }
  }
}

extern "C" void kernel_launch(void* const* d_in, const int* in_sizes, int n_in,
                              void* d_out, int out_size, void* d_ws, size_t ws_size,
                              hipStream_t stream) {
  const float* x   = (const float*)d_in[0];
  const float* roi = (const float*)d_in[1];
  const float* W1  = (const float*)d_in[2];
  const float* b1  = (const float*)d_in[3];
  const float* gng = (const float*)d_in[4];
  const float* gnb = (const float*)d_in[5];
  const float* W2  = (const float*)d_in[6];
  const float* b2  = (const float*)d_in[7];
  const float* W3  = (const float*)d_in[8];
  const float* b3  = (const float*)d_in[9];
  const float* bng = (const float*)d_in[10];
  const float* bnb = (const float*)d_in[11];
  const float* W4  = (const float*)d_in[12];
  const float* b4  = (const float*)d_in[13];
  float* out = (float*)d_out;

  char* ws = (char*)d_ws;
  float*  z    = (float*)(ws + Z_OFF);
  float*  p    = (float*)(ws + P_OFF);
  float*  ssum = (float*)(ws + SSUM_OFF);
  float*  ssq  = (float*)(ws + SSQ_OFF);
  float*  sa   = (float*)(ws + SA_OFF);
  float*  sd   = (float*)(ws + SD_OFF);
  __bf16* w2h  = (__bf16*)(ws + W2H_OFF);
  __bf16* w2l  = (__bf16*)(ws + W2L_OFF);
  __bf16* w4p  = (__bf16*)(ws + W4P_OFF);

  k0_prep<<<2116, 256, 0, stream>>>(W2, W4, w2h, w2l, w4p, ssum);
  k1_nodenet<<<NGRAPH, 256, 0, stream>>>(x, roi, W1, b1, gng, gnb, w2h, w2l, b2, z);
  k2_proj<<<256, 256, 0, stream>>>(z, W3, b3, p, ssum, ssq);
  k3_stats<<<1, 512, 0, stream>>>(ssum, ssq, bng, bnb, sa, sd);
  k4_final<<<256, 256, 0, stream>>>(p, sa, sd, w4p, b4, out);
}

// Round 5
// 266.995 us; speedup vs baseline: 1.4590x; 1.4590x over previous
//
#include <hip/hip_runtime.h>
#include <hip/hip_bf16.h>

typedef __bf16 bf16_8 __attribute__((ext_vector_type(8)));
typedef float f32x4 __attribute__((ext_vector_type(4)));

#define NNODES 113
#define NGRAPH 4096

// ---------------- ws layout (bytes) ----------------
// Proven-safe envelope from R2: [0, 11,608,064). Everything lives inside it.
// z region [0, 2,097,152) is reused for psum/psq AFTER k2 has consumed z.
#define Z_OFF    0u            // 4096*128*4 = 2,097,152 ; dead after k2
#define PSUM_OFF 0u            // 32*512*4 = 65,536  (aliases z; written by k2b, after z dead)
#define PSQ_OFF  65536u        // 32*512*4 = 65,536  (aliases z)
#define P_OFF    2097152u      // 4096*512*4 = 8,388,608
#define GC_OFF   10485760u     // 128*4 = 512 (gn quadform consts; k0 -> k1, private hole)
#define SA_OFF   10489856u     // 512*4
#define SD_OFF   10491904u     // 512*4
#define W2H_OFF  10493952u     // 16384*2
#define W2L_OFF  10526720u     // 16384*2
#define W4P_OFF  10559488u     // 524288*2 -> end 11,608,064 (== R2-proven bound)

// K0: pack W2 (hi+lo split) / W4 to bf16 B-fragment layout;
// block 2112 computes GroupNorm quadform constants per group:
//   gc[g*16+0..2] = mean of W1 cols in group, [3] = mean b1,
//   [4..9] = Gram upper-tri (off-diag doubled), [10..12] = 2*sum(b_c*w_c), [13] = sum(b_c^2)
// B-frag layout: elem ((kt*NT + nt)*64 + lane)*8 + j  <=  W[k][n],
//   k = kt*32 + (lane>>4)*8 + j, n = nt*16 + (lane&15)
__global__ __launch_bounds__(256) void k0_prep(
    const float* __restrict__ W2, const float* __restrict__ W4,
    const float* __restrict__ W1, const float* __restrict__ b1,
    __bf16* __restrict__ w2h, __bf16* __restrict__ w2l,
    __bf16* __restrict__ w4p, float* __restrict__ gc) {
  if (blockIdx.x == 2112) {
    int t = threadIdx.x;
    if (t < 128) {
      float a0 = W1[t], a1 = W1[128 + t], a2 = W1[256 + t], bb = b1[t];
      float p[14] = {a0, a1, a2, bb,
                     a0 * a0, 2.f * a0 * a1, 2.f * a0 * a2,
                     a1 * a1, 2.f * a1 * a2, a2 * a2,
                     2.f * bb * a0, 2.f * bb * a1, 2.f * bb * a2, bb * bb};
#pragma unroll
      for (int m = 1; m < 16; m <<= 1)
#pragma unroll
        for (int k = 0; k < 14; k++) p[k] += __shfl_xor(p[k], m, 64);
      if ((t & 15) == 0) {
        int gg = t >> 4;
#pragma unroll
        for (int k = 0; k < 4; k++) gc[gg * 16 + k] = p[k] * 0.0625f;
#pragma unroll
        for (int k = 4; k < 14; k++) gc[gg * 16 + k] = p[k];
      }
    }
    return;
  }
  int i = blockIdx.x * 256 + threadIdx.x;
  if (i < 524288) {                       // W4: NT=64 (N=1024), KT=16 (K=512)
    int j = i & 7, L = (i >> 3) & 63, nt = (i >> 9) & 63, kt = i >> 15;
    int k = kt * 32 + ((L >> 4) << 3) + j;
    int n = (nt << 4) + (L & 15);
    w4p[i] = (__bf16)W4[k * 1024 + n];
  } else if (i < 524288 + 16384) {        // W2: NT=8 (N=128), KT=4 (K=128), hi+lo
    int q = i - 524288;
    int j = q & 7, L = (q >> 3) & 63, nt = (q >> 9) & 7, kt = q >> 12;
    int k = kt * 32 + ((L >> 4) << 3) + j;
    int n = (nt << 4) + (L & 15);
    float v = W2[k * 128 + n];
    __bf16 h = (__bf16)v;
    w2h[q] = h;
    w2l[q] = (__bf16)(v - (float)h);
  }
}

// K1: per-graph node net + max pool. 1 block = 1 graph, 256 threads.
// Stats via quadform (no shuffles); fill at octet granularity (b128 LDS ops);
// split-bf16 3-pass MFMA for fp32-quality z. Fully deterministic per block.
__global__ __launch_bounds__(256) void k1_nodenet(
    const float* __restrict__ x, const float* __restrict__ roi,
    const float* __restrict__ W1, const float* __restrict__ b1,
    const float* __restrict__ gn_g, const float* __restrict__ gn_b,
    const __bf16* __restrict__ w2h, const __bf16* __restrict__ w2l,
    const float* __restrict__ b2, const float* __restrict__ gc,
    float* __restrict__ z) {
  __shared__ float4 xs4[128];
  __shared__ float2 st[904];         // (mu, rsqrt(var+eps)) per (n,g)
  __shared__ __bf16 A[128 * 264];    // per row: 16 octets x [8 hi | 8 lo]; pitch 264 el = 528B
  int t = threadIdx.x, g = blockIdx.x;
  int lane = t & 63, wv = t >> 6, quad = lane >> 4, l16 = lane & 15;

  // gconst registers for stats pass (group = t&7, invariant across iters)
  int gs = t & 7;
  float gcv[14];
#pragma unroll
  for (int j = 0; j < 14; j++) gcv[j] = gc[gs * 16 + j];

  // per-thread fill params: octet o = t&15 (invariant), channels c = o*8+j
  int o = t & 15;
  float pw0[8], pw1[8], pw2[8], pb[8], pg[8], pbe[8];
#pragma unroll
  for (int j = 0; j < 8; j++) {
    int c = o * 8 + j;
    pw0[j] = W1[c]; pw1[j] = W1[128 + c]; pw2[j] = W1[256 + c];
    pb[j] = b1[c];  pg[j] = gn_g[c];      pbe[j] = gn_b[c];
  }

  // prefetch B hi-fragments (32 VGPRs) while LDS phases run
  bf16_8 bh[4][2];
#pragma unroll
  for (int kt = 0; kt < 4; kt++)
#pragma unroll
    for (int ni = 0; ni < 2; ni++) {
      int nt = wv * 2 + ni;
      bh[kt][ni] = *(const bf16_8*)&w2h[((kt * 8 + nt) * 64 + lane) * 8];
    }

  // stage x*roi as float4 per node
  for (int i = t; i < NNODES * 3; i += 256) {
    float v = x[g * (NNODES * 3) + i] * roi[i];
    ((float*)xs4)[(i / 3) * 4 + (i % 3)] = v;
  }
  __syncthreads();

  // stats: mu, inv-std per (node, group) — pure FMA, no cross-lane
  for (int it = t; it < 904; it += 256) {
    int n = it >> 3;
    float4 xv = xs4[n];
    float mu = fmaf(xv.z, gcv[2], fmaf(xv.y, gcv[1], fmaf(xv.x, gcv[0], gcv[3])));
    float qf = fmaf(xv.z, gcv[12], fmaf(xv.y, gcv[11], fmaf(xv.x, gcv[10], gcv[13])));
    float u0 = fmaf(xv.z, gcv[6], fmaf(xv.y, gcv[5], xv.x * gcv[4]));
    qf = fmaf(xv.x, u0, qf);
    float u1 = fmaf(xv.z, gcv[8], xv.y * gcv[7]);
    qf = fmaf(xv.y, u1, qf);
    qf = fmaf(xv.z * xv.z, gcv[9], qf);
    float ms = qf * 0.0625f;
    float var = fmaxf(ms - mu * mu, 0.0f);
    st[it] = make_float2(mu, rsqrtf(var + 1e-5f));
  }
  __syncthreads();

  // fill A: 2048 items = 128 rows x 16 octets; 2 ds_write_b128 per item
  for (int it = t; it < 2048; it += 256) {
    int n = it >> 4;
    bf16_8 hv, lv;
    if (n < NNODES) {
      float4 xv = xs4[n];
      float2 s2 = st[n * 8 + (o >> 1)];
      float ia = s2.y, ib = -s2.x * s2.y;
#pragma unroll
      for (int j = 0; j < 8; j++) {
        float h = fmaf(xv.z, pw2[j], fmaf(xv.y, pw1[j], fmaf(xv.x, pw0[j], pb[j])));
        float y = fmaf(fmaf(h, ia, ib), pg[j], pbe[j]);
        y = (y > 0.0f) ? y : 0.2f * y;
        __bf16 hh = (__bf16)y;
        hv[j] = hh;
        lv[j] = (__bf16)(y - (float)hh);
      }
    } else {
#pragma unroll
      for (int j = 0; j < 8; j++) { hv[j] = (__bf16)0.f; lv[j] = (__bf16)0.f; }
    }
    *(bf16_8*)&A[n * 264 + o * 16] = hv;
    *(bf16_8*)&A[n * 264 + o * 16 + 8] = lv;
  }
  __syncthreads();

  // MFMA: [128x128] @ W2 ; wave w owns n-tiles {2w, 2w+1}; 3-pass split
  f32x4 acc[2][8];
#pragma unroll
  for (int a = 0; a < 2; a++)
#pragma unroll
    for (int m = 0; m < 8; m++) acc[a][m] = (f32x4){0.f, 0.f, 0.f, 0.f};

#pragma unroll
  for (int kt = 0; kt < 4; kt++) {
    bf16_8 ah[8], al[8];
#pragma unroll
    for (int mt = 0; mt < 8; mt++) {
      int base = (mt * 16 + l16) * 264 + (kt * 4 + quad) * 16;
      ah[mt] = *(const bf16_8*)&A[base];
      al[mt] = *(const bf16_8*)&A[base + 8];
    }
#pragma unroll
    for (int ni = 0; ni < 2; ni++) {
      int nt = wv * 2 + ni;
      bf16_8 blv = *(const bf16_8*)&w2l[((kt * 8 + nt) * 64 + lane) * 8];
#pragma unroll
      for (int mt = 0; mt < 8; mt++) {
        acc[ni][mt] = __builtin_amdgcn_mfma_f32_16x16x32_bf16(ah[mt], bh[kt][ni], acc[ni][mt], 0, 0, 0);
        acc[ni][mt] = __builtin_amdgcn_mfma_f32_16x16x32_bf16(al[mt], bh[kt][ni], acc[ni][mt], 0, 0, 0);
        acc[ni][mt] = __builtin_amdgcn_mfma_f32_16x16x32_bf16(ah[mt], blv, acc[ni][mt], 0, 0, 0);
      }
    }
  }

  // Column max over valid rows (C layout: row = quad*4+r, col = lane&15), + b2
#pragma unroll
  for (int ni = 0; ni < 2; ni++) {
    int nt = wv * 2 + ni;
    float m = -3.4e38f;
#pragma unroll
    for (int mt = 0; mt < 8; mt++) {
#pragma unroll
      for (int r = 0; r < 4; r++) {
        int row = mt * 16 + quad * 4 + r;
        if (row < NNODES) m = fmaxf(m, acc[ni][mt][r]);
      }
    }
    m = fmaxf(m, __shfl_xor(m, 16, 64));
    m = fmaxf(m, __shfl_xor(m, 32, 64));
    if (quad == 0) {
      int col = nt * 16 + l16;
      z[g * 128 + col] = m + b2[col];
    }
  }
}

// K2: p = z @ W3 + b3 (fp32), 8 rows/block (512 blocks). No stats (determinism).
__global__ __launch_bounds__(256) void k2_proj(
    const float* __restrict__ z, const float* __restrict__ W3,
    const float* __restrict__ b3, float* __restrict__ p) {
  __shared__ float zs[8 * 128];
  int t = threadIdx.x;
  int gr0 = blockIdx.x * 8;
  for (int i = t; i < 1024; i += 256) zs[i] = z[gr0 * 128 + i];
  int wv = t >> 6;
  int r0 = wv * 2;
  int c0 = (t & 63) * 8;
  float bb[8];
#pragma unroll
  for (int b = 0; b < 8; b++) bb[b] = b3[c0 + b];
  float acc[2][8];
#pragma unroll
  for (int a = 0; a < 2; a++)
#pragma unroll
    for (int b = 0; b < 8; b++) acc[a][b] = 0.0f;
  __syncthreads();

  for (int k = 0; k < 128; k++) {
    float4 wA = *(const float4*)&W3[k * 512 + c0];
    float4 wB = *(const float4*)&W3[k * 512 + c0 + 4];
#pragma unroll
    for (int a = 0; a < 2; a++) {
      float zv = zs[(r0 + a) * 128 + k];
      acc[a][0] = fmaf(zv, wA.x, acc[a][0]);
      acc[a][1] = fmaf(zv, wA.y, acc[a][1]);
      acc[a][2] = fmaf(zv, wA.z, acc[a][2]);
      acc[a][3] = fmaf(zv, wA.w, acc[a][3]);
      acc[a][4] = fmaf(zv, wB.x, acc[a][4]);
      acc[a][5] = fmaf(zv, wB.y, acc[a][5]);
      acc[a][6] = fmaf(zv, wB.z, acc[a][6]);
      acc[a][7] = fmaf(zv, wB.w, acc[a][7]);
    }
  }

#pragma unroll
  for (int a = 0; a < 2; a++) {
    int row = gr0 + r0 + a;
    float4 o0 = make_float4(acc[a][0] + bb[0], acc[a][1] + bb[1], acc[a][2] + bb[2], acc[a][3] + bb[3]);
    float4 o1 = make_float4(acc[a][4] + bb[4], acc[a][5] + bb[5], acc[a][6] + bb[6], acc[a][7] + bb[7]);
    *(float4*)&p[row * 512 + c0] = o0;
    *(float4*)&p[row * 512 + c0 + 4] = o1;
  }
}

// K2b: deterministic per-block channel partials of p (32 blocks x 128 rows).
// Fixed-order register accumulation; disjoint plain stores (no atomics).
// psum/psq live in the (now dead) z region — strictly after k2 consumed z.
__global__ __launch_bounds__(256) void k2b_partial(
    const float* __restrict__ p, float* __restrict__ psum, float* __restrict__ psq) {
  int t = threadIdx.x, b = blockIdx.x;
  int r0 = b * 128;
  float s0 = 0.f, q0 = 0.f, s1 = 0.f, q1 = 0.f;
  for (int r = 0; r < 128; r++) {
    float v0 = p[(r0 + r) * 512 + t];
    float v1 = p[(r0 + r) * 512 + t + 256];
    s0 += v0; q0 = fmaf(v0, v0, q0);
    s1 += v1; q1 = fmaf(v1, v1, q1);
  }
  psum[b * 512 + t] = s0;
  psum[b * 512 + t + 256] = s1;
  psq[b * 512 + t] = q0;
  psq[b * 512 + t + 256] = q1;
}

// K3: fixed-order reduce of 32 partials -> BN scale a, shift d
__global__ __launch_bounds__(512) void k3_stats(
    const float* __restrict__ psum, const float* __restrict__ psq,
    const float* __restrict__ bn_g, const float* __restrict__ bn_b,
    float* __restrict__ sa, float* __restrict__ sd) {
  int c = threadIdx.x;
  float s = 0.f, q = 0.f;
#pragma unroll 4
  for (int b = 0; b < 32; b++) {
    s += psum[b * 512 + c];
    q += psq[b * 512 + c];
  }
  float mu = s * (1.0f / 4096.0f);
  float var = fmaxf(q * (1.0f / 4096.0f) - mu * mu, 0.0f);
  float sc = bn_g[c] * rsqrtf(var + 1e-5f);
  sa[c] = sc;
  sd[c] = bn_b[c] - mu * sc;
}

// K4: out = L2norm( relu(p*a+d) @ W4 + b4 ), 16 rows/block via MFMA
__global__ __launch_bounds__(256) void k4_final(
    const float* __restrict__ p, const float* __restrict__ sa,
    const float* __restrict__ sd, const __bf16* __restrict__ w4p,
    const float* __restrict__ b4, float* __restrict__ out) {
  __shared__ __bf16 As[16 * 520];
  __shared__ float rred[4 * 16];
  int t = threadIdx.x;
  int gr0 = blockIdx.x * 16;

  for (int i = t; i < 16 * 512; i += 256) {
    int row = i >> 9, col = i & 511;
    float v = fmaf(p[gr0 * 512 + i], sa[col], sd[col]);
    v = fmaxf(v, 0.0f);
    As[row * 520 + col] = (__bf16)v;
  }
  __syncthreads();

  int lane = t & 63, wv = t >> 6, quad = lane >> 4, l16 = lane & 15;
  f32x4 acc[16];
#pragma unroll
  for (int ni = 0; ni < 16; ni++) acc[ni] = (f32x4){0.f, 0.f, 0.f, 0.f};

  for (int kt = 0; kt < 16; kt++) {
    bf16_8 afr = *(const bf16_8*)&As[l16 * 520 + kt * 32 + quad * 8];
#pragma unroll
    for (int ni = 0; ni < 16; ni++) {
      int nt = wv * 16 + ni;
      bf16_8 bfr = *(const bf16_8*)&w4p[((kt * 64 + nt) * 64 + lane) * 8];
      acc[ni] = __builtin_amdgcn_mfma_f32_16x16x32_bf16(afr, bfr, acc[ni], 0, 0, 0);
    }
  }

  float rs[4] = {0.f, 0.f, 0.f, 0.f};
#pragma unroll
  for (int ni = 0; ni < 16; ni++) {
    int col = (wv * 16 + ni) * 16 + l16;
    float bv = b4[col];
#pragma unroll
    for (int r = 0; r < 4; r++) {
      float v = acc[ni][r] + bv;
      acc[ni][r] = v;
      rs[r] = fmaf(v, v, rs[r]);
    }
  }
#pragma unroll
  for (int m = 1; m < 16; m <<= 1) {
#pragma unroll
    for (int r = 0; r < 4; r++) rs[r] += __shfl_xor(rs[r], m, 64);
  }
  if (l16 == 0) {
#pragma unroll
    for (int r = 0; r < 4; r++) rred[wv * 16 + quad * 4 + r] = rs[r];
  }
  __syncthreads();

  float inv[4];
#pragma unroll
  for (int r = 0; r < 4; r++) {
    int row = quad * 4 + r;
    float s = rred[row] + rred[16 + row] + rred[32 + row] + rred[48 + row];
    inv[r] = 1.0f / fmaxf(sqrtf(s), 1e-12f);
  }
#pragma unroll
  for (int ni = 0; ni < 16; ni++) {
    int col = (wv * 16 + ni) * 16 + l16;
#pragma unroll
    for (int r = 0; r < 4; r++) {
      int row = gr0 + quad * 4 + r;
      out[row * 1024 + col] = acc[ni][r] * inv[r];
    }
  }
}

extern "C" void kernel_launch(void* const* d_in, const int* in_sizes, int n_in,
                              void* d_out, int out_size, void* d_ws, size_t ws_size,
                              hipStream_t stream) {
  const float* x   = (const float*)d_in[0];
  const float* roi = (const float*)d_in[1];
  const float* W1  = (const float*)d_in[2];
  const float* b1  = (const float*)d_in[3];
  const float* gng = (const float*)d_in[4];
  const float* gnb = (const float*)d_in[5];
  const float* W2  = (const float*)d_in[6];
  const float* b2  = (const float*)d_in[7];
  const float* W3  = (const float*)d_in[8];
  const float* b3  = (const float*)d_in[9];
  const float* bng = (const float*)d_in[10];
  const float* bnb = (const float*)d_in[11];
  const float* W4  = (const float*)d_in[12];
  const float* b4  = (const float*)d_in[13];
  float* out = (float*)d_out;

  char* ws = (char*)d_ws;
  float*  z    = (float*)(ws + Z_OFF);
  float*  psum = (float*)(ws + PSUM_OFF);  // aliases z: live only after k2
  float*  psq  = (float*)(ws + PSQ_OFF);   // aliases z: live only after k2
  float*  p    = (float*)(ws + P_OFF);
  float*  gc   = (float*)(ws + GC_OFF);
  float*  sa   = (float*)(ws + SA_OFF);
  float*  sd   = (float*)(ws + SD_OFF);
  __bf16* w2h  = (__bf16*)(ws + W2H_OFF);
  __bf16* w2l  = (__bf16*)(ws + W2L_OFF);
  __bf16* w4p  = (__bf16*)(ws + W4P_OFF);

  k0_prep<<<2113, 256, 0, stream>>>(W2, W4, W1, b1, w2h, w2l, w4p, gc);
  k1_nodenet<<<NGRAPH, 256, 0, stream>>>(x, roi, W1, b1, gng, gnb, w2h, w2l, b2, gc, z);
  k2_proj<<<512, 256, 0, stream>>>(z, W3, b3, p);
  k2b_partial<<<32, 256, 0, stream>>>(p, psum, psq);
  k3_stats<<<1, 512, 0, stream>>>(psum, psq, bng, bnb, sa, sd);
  k4_final<<<256, 256, 0, stream>>>(p, sa, sd, w4p, b4, out);
}

// Round 6
// 188.165 us; speedup vs baseline: 2.0702x; 1.4189x over previous
//
#include <hip/hip_runtime.h>
#include <hip/hip_bf16.h>

typedef _Float16 f16_8 __attribute__((ext_vector_type(8)));
typedef float f32x4 __attribute__((ext_vector_type(4)));

#define NNODES 113
#define NGRAPH 4096

// ---------------- ws layout (bytes), proven envelope [0, 11,608,064) -------
// z [0, 2 MB) dead after k2; psum/psq/psn alias it afterwards.
#define Z_OFF    0u
#define PSUM_OFF 0u            // 32*512*4 (k2b -> k3)
#define PSQ_OFF  65536u        // 32*512*4
#define PSN_OFF  131072u       // 8*4096*4 = 131072 (k4a -> k4b)
#define P_OFF    2097152u      // 4096*512*4
#define GC_OFF   10485760u     // 128*4
#define SA_OFF   10489856u     // 512*4
#define SD_OFF   10491904u     // 512*4
#define W2P_OFF  10493952u     // 16384*2 fp16
#define W4P_OFF  10559488u     // 524288*2 fp16 -> end 11,608,064

// K0: blocks 0..63: W4 -> fp16 B-frag pack via LDS transpose (coalesced both sides)
//     blocks 64..71: W2 -> fp16 B-frag pack; block 72: GN quadform consts.
// B-frag: elem ((kt*NT+nt)*64+L)*8+j <= W[k][n], k=kt*32+(L>>4)*8+j, n=nt*16+(L&15)
__global__ __launch_bounds__(256) void k0_prep(
    const float* __restrict__ W2, const float* __restrict__ W4,
    const float* __restrict__ W1, const float* __restrict__ b1,
    _Float16* __restrict__ w2p, _Float16* __restrict__ w4p,
    float* __restrict__ gc) {
  int b = blockIdx.x, t = threadIdx.x;
  if (b < 64) {                     // W4: tile kt (32 k) x nc (256 n)
    __shared__ _Float16 T[32 * 264];
    int kt = b >> 2, nc = b & 3;
#pragma unroll
    for (int rr = 0; rr < 4; rr++) {
      int row = rr * 8 + (t >> 5), col8 = (t & 31) * 8;
      const float* src = &W4[(kt * 32 + row) * 1024 + nc * 256 + col8];
      float4 a0 = *(const float4*)src, a1 = *(const float4*)(src + 4);
      f16_8 v = {(_Float16)a0.x, (_Float16)a0.y, (_Float16)a0.z, (_Float16)a0.w,
                 (_Float16)a1.x, (_Float16)a1.y, (_Float16)a1.z, (_Float16)a1.w};
      *(f16_8*)&T[row * 264 + col8] = v;
    }
    __syncthreads();
#pragma unroll
    for (int it = 0; it < 4; it++) {
      int idx = it * 256 + t;
      int ntl = idx >> 6, L = idx & 63;
      f16_8 v;
#pragma unroll
      for (int j = 0; j < 8; j++)
        v[j] = T[((L >> 4) * 8 + j) * 264 + ntl * 16 + (L & 15)];
      *(f16_8*)&w4p[((kt * 64 + nc * 16 + ntl) * 64 + L) * 8] = v;
    }
  } else if (b < 72) {              // W2 pack (small)
    int q0 = (b - 64) * 256 + t;
    int L = q0 & 63, nt = (q0 >> 6) & 7, kt = q0 >> 9;
    f16_8 v;
#pragma unroll
    for (int j = 0; j < 8; j++)
      v[j] = (_Float16)W2[(kt * 32 + ((L >> 4) << 3) + j) * 128 + (nt << 4) + (L & 15)];
    *(f16_8*)&w2p[((kt * 8 + nt) * 64 + L) * 8] = v;
  } else {                          // GN quadform consts
    if (t < 128) {
      float a0 = W1[t], a1 = W1[128 + t], a2 = W1[256 + t], bb = b1[t];
      float p[14] = {a0, a1, a2, bb,
                     a0 * a0, 2.f * a0 * a1, 2.f * a0 * a2,
                     a1 * a1, 2.f * a1 * a2, a2 * a2,
                     2.f * bb * a0, 2.f * bb * a1, 2.f * bb * a2, bb * bb};
#pragma unroll
      for (int m = 1; m < 16; m <<= 1)
#pragma unroll
        for (int k = 0; k < 14; k++) p[k] += __shfl_xor(p[k], m, 64);
      if ((t & 15) == 0) {
        int gg = t >> 4;
#pragma unroll
        for (int k = 0; k < 4; k++) gc[gg * 16 + k] = p[k] * 0.0625f;
#pragma unroll
        for (int k = 4; k < 14; k++) gc[gg * 16 + k] = p[k];
      }
    }
  }
}

// K1: per-graph node net + max pool; fp16 single-pass MFMA (fp16 precision is
// ~8x tighter than bf16 -> z err ~1e-3 after BN amplification). 3 blocks/CU.
__global__ __launch_bounds__(256, 3) void k1_nodenet(
    const float* __restrict__ x, const float* __restrict__ roi,
    const float* __restrict__ W1, const float* __restrict__ b1,
    const float* __restrict__ gn_g, const float* __restrict__ gn_b,
    const _Float16* __restrict__ w2p, const float* __restrict__ b2,
    const float* __restrict__ gc, float* __restrict__ z) {
  __shared__ float4 xs4[128];
  __shared__ float2 st[904];
  __shared__ _Float16 A[128 * 136];   // pitch 136 fp16 = 272 B
  int t = threadIdx.x, g = blockIdx.x;
  int lane = t & 63, wv = t >> 6, quad = lane >> 4, l16 = lane & 15;

  int gs = t & 7;
  float gcv[14];
#pragma unroll
  for (int j = 0; j < 14; j++) gcv[j] = gc[gs * 16 + j];

  int o = t & 15;
  float pw0[8], pw1[8], pw2[8], pb[8], pg[8], pbe[8];
#pragma unroll
  for (int j = 0; j < 8; j++) {
    int c = o * 8 + j;
    pw0[j] = W1[c]; pw1[j] = W1[128 + c]; pw2[j] = W1[256 + c];
    pb[j] = b1[c];  pg[j] = gn_g[c];      pbe[j] = gn_b[c];
  }

  f16_8 bh[4][2];
#pragma unroll
  for (int kt = 0; kt < 4; kt++)
#pragma unroll
    for (int ni = 0; ni < 2; ni++)
      bh[kt][ni] = *(const f16_8*)&w2p[((kt * 8 + wv * 2 + ni) * 64 + lane) * 8];

  for (int i = t; i < NNODES * 3; i += 256) {
    float v = x[g * (NNODES * 3) + i] * roi[i];
    ((float*)xs4)[(i / 3) * 4 + (i % 3)] = v;
  }
  __syncthreads();

  for (int it = t; it < 904; it += 256) {
    int n = it >> 3;
    float4 xv = xs4[n];
    float mu = fmaf(xv.z, gcv[2], fmaf(xv.y, gcv[1], fmaf(xv.x, gcv[0], gcv[3])));
    float qf = fmaf(xv.z, gcv[12], fmaf(xv.y, gcv[11], fmaf(xv.x, gcv[10], gcv[13])));
    float u0 = fmaf(xv.z, gcv[6], fmaf(xv.y, gcv[5], xv.x * gcv[4]));
    qf = fmaf(xv.x, u0, qf);
    float u1 = fmaf(xv.z, gcv[8], xv.y * gcv[7]);
    qf = fmaf(xv.y, u1, qf);
    qf = fmaf(xv.z * xv.z, gcv[9], qf);
    float var = fmaxf(qf * 0.0625f - mu * mu, 0.0f);
    st[it] = make_float2(mu, rsqrtf(var + 1e-5f));
  }
  __syncthreads();

  for (int it = t; it < 2048; it += 256) {
    int n = it >> 4;
    f16_8 hv;
    if (n < NNODES) {
      float4 xv = xs4[n];
      float2 s2 = st[n * 8 + (o >> 1)];
      float ia = s2.y, ib = -s2.x * s2.y;
#pragma unroll
      for (int j = 0; j < 8; j++) {
        float h = fmaf(xv.z, pw2[j], fmaf(xv.y, pw1[j], fmaf(xv.x, pw0[j], pb[j])));
        float y = fmaf(fmaf(h, ia, ib), pg[j], pbe[j]);
        y = (y > 0.0f) ? y : 0.2f * y;
        hv[j] = (_Float16)y;
      }
    } else {
#pragma unroll
      for (int j = 0; j < 8; j++) hv[j] = (_Float16)0.f;
    }
    *(f16_8*)&A[n * 136 + o * 8] = hv;
  }
  __syncthreads();

  f32x4 acc[2][8];
#pragma unroll
  for (int a = 0; a < 2; a++)
#pragma unroll
    for (int m = 0; m < 8; m++) acc[a][m] = (f32x4){0.f, 0.f, 0.f, 0.f};

#pragma unroll
  for (int kt = 0; kt < 4; kt++) {
    f16_8 ah[8];
#pragma unroll
    for (int mt = 0; mt < 8; mt++)
      ah[mt] = *(const f16_8*)&A[(mt * 16 + l16) * 136 + kt * 32 + quad * 8];
#pragma unroll
    for (int ni = 0; ni < 2; ni++)
#pragma unroll
      for (int mt = 0; mt < 8; mt++)
        acc[ni][mt] = __builtin_amdgcn_mfma_f32_16x16x32_f16(ah[mt], bh[kt][ni], acc[ni][mt], 0, 0, 0);
  }

#pragma unroll
  for (int ni = 0; ni < 2; ni++) {
    int nt = wv * 2 + ni;
    float m = -3.4e38f;
#pragma unroll
    for (int mt = 0; mt < 8; mt++)
#pragma unroll
      for (int r = 0; r < 4; r++) {
        int row = mt * 16 + quad * 4 + r;
        if (row < NNODES) m = fmaxf(m, acc[ni][mt][r]);
      }
    m = fmaxf(m, __shfl_xor(m, 16, 64));
    m = fmaxf(m, __shfl_xor(m, 32, 64));
    if (quad == 0) {
      int col = nt * 16 + l16;
      z[g * 128 + col] = m + b2[col];
    }
  }
}

// K2: p = z @ W3 + b3 fp32; 16 rows/block, 256 blocks, 4 rows/thread.
__global__ __launch_bounds__(256) void k2_proj(
    const float* __restrict__ z, const float* __restrict__ W3,
    const float* __restrict__ b3, float* __restrict__ p) {
  __shared__ float zs[16 * 128];
  int t = threadIdx.x;
  int gr0 = blockIdx.x * 16;
  for (int i = t; i < 2048; i += 256) zs[i] = z[gr0 * 128 + i];
  int wv = t >> 6, r0 = wv * 4, c0 = (t & 63) * 8;
  float bb[8];
#pragma unroll
  for (int b = 0; b < 8; b++) bb[b] = b3[c0 + b];
  float acc[4][8];
#pragma unroll
  for (int a = 0; a < 4; a++)
#pragma unroll
    for (int b = 0; b < 8; b++) acc[a][b] = 0.0f;
  __syncthreads();

#pragma unroll 4
  for (int k = 0; k < 128; k++) {
    float4 wA = *(const float4*)&W3[k * 512 + c0];
    float4 wB = *(const float4*)&W3[k * 512 + c0 + 4];
#pragma unroll
    for (int a = 0; a < 4; a++) {
      float zv = zs[(r0 + a) * 128 + k];
      acc[a][0] = fmaf(zv, wA.x, acc[a][0]);
      acc[a][1] = fmaf(zv, wA.y, acc[a][1]);
      acc[a][2] = fmaf(zv, wA.z, acc[a][2]);
      acc[a][3] = fmaf(zv, wA.w, acc[a][3]);
      acc[a][4] = fmaf(zv, wB.x, acc[a][4]);
      acc[a][5] = fmaf(zv, wB.y, acc[a][5]);
      acc[a][6] = fmaf(zv, wB.z, acc[a][6]);
      acc[a][7] = fmaf(zv, wB.w, acc[a][7]);
    }
  }
#pragma unroll
  for (int a = 0; a < 4; a++) {
    int row = gr0 + r0 + a;
    float4 o0 = make_float4(acc[a][0] + bb[0], acc[a][1] + bb[1], acc[a][2] + bb[2], acc[a][3] + bb[3]);
    float4 o1 = make_float4(acc[a][4] + bb[4], acc[a][5] + bb[5], acc[a][6] + bb[6], acc[a][7] + bb[7]);
    *(float4*)&p[row * 512 + c0] = o0;
    *(float4*)&p[row * 512 + c0 + 4] = o1;
  }
}

// K2b/K3: deterministic BN stats (fixed-order partials, no atomics)
__global__ __launch_bounds__(256) void k2b_partial(
    const float* __restrict__ p, float* __restrict__ psum, float* __restrict__ psq) {
  int t = threadIdx.x, b = blockIdx.x;
  int r0 = b * 128;
  float s0 = 0.f, q0 = 0.f, s1 = 0.f, q1 = 0.f;
  for (int r = 0; r < 128; r++) {
    float v0 = p[(r0 + r) * 512 + t];
    float v1 = p[(r0 + r) * 512 + t + 256];
    s0 += v0; q0 = fmaf(v0, v0, q0);
    s1 += v1; q1 = fmaf(v1, v1, q1);
  }
  psum[b * 512 + t] = s0;
  psum[b * 512 + t + 256] = s1;
  psq[b * 512 + t] = q0;
  psq[b * 512 + t + 256] = q1;
}

__global__ __launch_bounds__(512) void k3_stats(
    const float* __restrict__ psum, const float* __restrict__ psq,
    const float* __restrict__ bn_g, const float* __restrict__ bn_b,
    float* __restrict__ sa, float* __restrict__ sd) {
  int c = threadIdx.x;
  float s = 0.f, q = 0.f;
#pragma unroll 4
  for (int b = 0; b < 32; b++) {
    s += psum[b * 512 + c];
    q += psq[b * 512 + c];
  }
  float mu = s * (1.0f / 4096.0f);
  float var = fmaxf(q * (1.0f / 4096.0f) - mu * mu, 0.0f);
  float sc = bn_g[c] * rsqrtf(var + 1e-5f);
  sa[c] = sc;
  sd[c] = bn_b[c] - mu * sc;
}

// K4a: 2D-tiled (rb 32 x cb 8; rb = b&31 keeps cb-siblings on one XCD).
// Per kt: stage p-tile -> BN+ReLU+fp16 -> LDS; reg-pipelined loads; MFMA.
// Writes unnormalized out + per-(cb,row) sumsq partials.
__global__ __launch_bounds__(256) void k4a_gemm(
    const float* __restrict__ p, const float* __restrict__ sa,
    const float* __restrict__ sd, const _Float16* __restrict__ w4p,
    const float* __restrict__ b4, float* __restrict__ out,
    float* __restrict__ psn) {
  __shared__ _Float16 T[128 * 40];      // 128 rows x 32 k, pitch 40
  __shared__ float sas[512], sds[512];
  __shared__ float rred[4 * 128];
  int t = threadIdx.x;
  int rb = blockIdx.x & 31, cb = blockIdx.x >> 5;
  int lane = t & 63, wv = t >> 6, quad = lane >> 4, l16 = lane & 15;

  for (int i = t; i < 512; i += 256) { sas[i] = sa[i]; sds[i] = sd[i]; }

  int srow = t >> 2, scc = t & 3;       // staging: thread -> (row srow, chunk scc) + (row srow+64)
  f32x4 acc[2][8];
#pragma unroll
  for (int a = 0; a < 2; a++)
#pragma unroll
    for (int m = 0; m < 8; m++) acc[a][m] = (f32x4){0.f, 0.f, 0.f, 0.f};

  float4 pa[2][2];
  // preload kt=0 p-fragments
#pragma unroll
  for (int i2 = 0; i2 < 2; i2++) {
    const float* src = &p[(rb * 128 + srow + i2 * 64) * 512 + scc * 8];
    pa[i2][0] = *(const float4*)src;
    pa[i2][1] = *(const float4*)(src + 4);
  }
  f16_8 b0[2];
#pragma unroll
  for (int ni = 0; ni < 2; ni++)
    b0[ni] = *(const f16_8*)&w4p[((0 * 64 + cb * 8 + wv * 2 + ni) * 64 + lane) * 8];

  for (int kt = 0; kt < 16; kt++) {
    __syncthreads();  // T free (prior MFMA reads done)
#pragma unroll
    for (int i2 = 0; i2 < 2; i2++) {
      int row = srow + i2 * 64;
      int kc = kt * 32 + scc * 8;
      f16_8 v;
#pragma unroll
      for (int j = 0; j < 4; j++) {
        float vv = fmaf(((float*)&pa[i2][0])[j], sas[kc + j], sds[kc + j]);
        v[j] = (_Float16)fmaxf(vv, 0.0f);
      }
#pragma unroll
      for (int j = 0; j < 4; j++) {
        float vv = fmaf(((float*)&pa[i2][1])[j], sas[kc + 4 + j], sds[kc + 4 + j]);
        v[4 + j] = (_Float16)fmaxf(vv, 0.0f);
      }
      *(f16_8*)&T[row * 40 + scc * 8] = v;
    }
    __syncthreads();  // T ready
    if (kt < 15) {    // prefetch next kt (overlaps with MFMA below)
#pragma unroll
      for (int i2 = 0; i2 < 2; i2++) {
        const float* src = &p[(rb * 128 + srow + i2 * 64) * 512 + (kt + 1) * 32 + scc * 8];
        pa[i2][0] = *(const float4*)src;
        pa[i2][1] = *(const float4*)(src + 4);
      }
    }
    f16_8 bcur[2] = {b0[0], b0[1]};
    if (kt < 15) {
#pragma unroll
      for (int ni = 0; ni < 2; ni++)
        b0[ni] = *(const f16_8*)&w4p[(((kt + 1) * 64 + cb * 8 + wv * 2 + ni) * 64 + lane) * 8];
    }
#pragma unroll
    for (int mt = 0; mt < 8; mt++) {
      f16_8 af = *(const f16_8*)&T[(mt * 16 + l16) * 40 + quad * 8];
      acc[0][mt] = __builtin_amdgcn_mfma_f32_16x16x32_f16(af, bcur[0], acc[0][mt], 0, 0, 0);
      acc[1][mt] = __builtin_amdgcn_mfma_f32_16x16x32_f16(af, bcur[1], acc[1][mt], 0, 0, 0);
    }
  }

  // epilogue: +b4, store unnormalized, row sumsq partials
  float rsq[8][4];
#pragma unroll
  for (int mt = 0; mt < 8; mt++)
#pragma unroll
    for (int r = 0; r < 4; r++) rsq[mt][r] = 0.0f;
#pragma unroll
  for (int ni = 0; ni < 2; ni++) {
    int col = cb * 128 + (wv * 2 + ni) * 16 + l16;
    float bv = b4[col];
#pragma unroll
    for (int mt = 0; mt < 8; mt++)
#pragma unroll
      for (int r = 0; r < 4; r++) {
        float v = acc[ni][mt][r] + bv;
        int row = rb * 128 + mt * 16 + quad * 4 + r;
        out[row * 1024 + col] = v;
        rsq[mt][r] = fmaf(v, v, rsq[mt][r]);
      }
  }
#pragma unroll
  for (int m = 1; m < 16; m <<= 1)
#pragma unroll
    for (int mt = 0; mt < 8; mt++)
#pragma unroll
      for (int r = 0; r < 4; r++) rsq[mt][r] += __shfl_xor(rsq[mt][r], m, 64);
  if (l16 == 0) {
#pragma unroll
    for (int mt = 0; mt < 8; mt++)
#pragma unroll
      for (int r = 0; r < 4; r++)
        rred[wv * 128 + mt * 16 + quad * 4 + r] = rsq[mt][r];
  }
  __syncthreads();
  if (t < 128) {
    float s = rred[t] + rred[128 + t] + rred[256 + t] + rred[384 + t];
    psn[cb * 4096 + rb * 128 + t] = s;
  }
}

// K4b: in-place L2 normalize of out, 4 rows/block.
__global__ __launch_bounds__(256) void k4b_norm(
    float* __restrict__ out, const float* __restrict__ psn) {
  int t = threadIdx.x;
  int row = blockIdx.x * 4 + (t >> 6);
  float s = 0.f;
#pragma unroll
  for (int cb = 0; cb < 8; cb++) s += psn[cb * 4096 + row];
  float inv = 1.0f / fmaxf(sqrtf(s), 1e-12f);
  int c0 = (t & 63) * 4;
#pragma unroll
  for (int it = 0; it < 4; it++) {
    float4 v = *(const float4*)&out[row * 1024 + it * 256 + c0];
    v.x *= inv; v.y *= inv; v.z *= inv; v.w *= inv;
    *(float4*)&out[row * 1024 + it * 256 + c0] = v;
  }
}

extern "C" void kernel_launch(void* const* d_in, const int* in_sizes, int n_in,
                              void* d_out, int out_size, void* d_ws, size_t ws_size,
                              hipStream_t stream) {
  const float* x   = (const float*)d_in[0];
  const float* roi = (const float*)d_in[1];
  const float* W1  = (const float*)d_in[2];
  const float* b1  = (const float*)d_in[3];
  const float* gng = (const float*)d_in[4];
  const float* gnb = (const float*)d_in[5];
  const float* W2  = (const float*)d_in[6];
  const float* b2  = (const float*)d_in[7];
  const float* W3  = (const float*)d_in[8];
  const float* b3  = (const float*)d_in[9];
  const float* bng = (const float*)d_in[10];
  const float* bnb = (const float*)d_in[11];
  const float* W4  = (const float*)d_in[12];
  const float* b4  = (const float*)d_in[13];
  float* out = (float*)d_out;

  char* ws = (char*)d_ws;
  float*    z    = (float*)(ws + Z_OFF);
  float*    psum = (float*)(ws + PSUM_OFF);
  float*    psq  = (float*)(ws + PSQ_OFF);
  float*    psn  = (float*)(ws + PSN_OFF);
  float*    p    = (float*)(ws + P_OFF);
  float*    gc   = (float*)(ws + GC_OFF);
  float*    sa   = (float*)(ws + SA_OFF);
  float*    sd   = (float*)(ws + SD_OFF);
  _Float16* w2p  = (_Float16*)(ws + W2P_OFF);
  _Float16* w4p  = (_Float16*)(ws + W4P_OFF);

  k0_prep<<<73, 256, 0, stream>>>(W2, W4, W1, b1, w2p, w4p, gc);
  k1_nodenet<<<NGRAPH, 256, 0, stream>>>(x, roi, W1, b1, gng, gnb, w2p, b2, gc, z);
  k2_proj<<<256, 256, 0, stream>>>(z, W3, b3, p);
  k2b_partial<<<32, 256, 0, stream>>>(p, psum, psq);
  k3_stats<<<1, 512, 0, stream>>>(psum, psq, bng, bnb, sa, sd);
  k4a_gemm<<<256, 256, 0, stream>>>(p, sa, sd, w4p, b4, out, psn);
  k4b_norm<<<1024, 256, 0, stream>>>(out, psn);
}

// Round 7
// 181.336 us; speedup vs baseline: 2.1481x; 1.0377x over previous
//
#include <hip/hip_runtime.h>
#include <hip/hip_bf16.h>

typedef _Float16 f16_8 __attribute__((ext_vector_type(8)));
typedef _Float16 f16_2 __attribute__((ext_vector_type(2)));
typedef float f32x4 __attribute__((ext_vector_type(4)));

#define NNODES 113
#define NGRAPH 4096

// ---------------- ws layout (bytes), proven envelope [0, 11,608,064) -------
#define Z_OFF    0u
#define PSUM_OFF 0u            // 32*512*4 (k2b -> k3), aliases dead z
#define PSQ_OFF  65536u
#define PSN_OFF  131072u       // 8*4096*4 (k4a -> k4b), aliases dead z
#define P_OFF    2097152u      // 4096*512*4
#define GC_OFF   10485760u     // 128*4
#define SA_OFF   10489856u     // 512*4
#define SD_OFF   10491904u     // 512*4
#define W2P_OFF  10493952u     // 16384*2 fp16
#define W4P_OFF  10559488u     // 524288*2 fp16 -> end 11,608,064

// K0: blocks 0..255: W4 -> fp16 B-frag pack via LDS transpose (256-way parallel)
//     blocks 256..263: W2 pack; block 264: GN quadform consts.
// B-frag: elem ((kt*NT+nt)*64+L)*8+j <= W[k][n], k=kt*32+(L>>4)*8+j, n=nt*16+(L&15)
__global__ __launch_bounds__(256) void k0_prep(
    const float* __restrict__ W2, const float* __restrict__ W4,
    const float* __restrict__ W1, const float* __restrict__ b1,
    _Float16* __restrict__ w2p, _Float16* __restrict__ w4p,
    float* __restrict__ gc) {
  int b = blockIdx.x, t = threadIdx.x;
  if (b < 256) {                    // W4 tile: 32 k-rows x 64 n-cols
    __shared__ _Float16 T[32 * 72];
    int kt = b >> 4, nc = b & 15;
    int row = t >> 3, c8 = (t & 7) * 8;
    const float* src = &W4[(kt * 32 + row) * 1024 + nc * 64 + c8];
    float4 a0 = *(const float4*)src;
    float4 a1 = *(const float4*)(src + 4);
    f16_8 v = {(_Float16)a0.x, (_Float16)a0.y, (_Float16)a0.z, (_Float16)a0.w,
               (_Float16)a1.x, (_Float16)a1.y, (_Float16)a1.z, (_Float16)a1.w};
    *(f16_8*)&T[row * 72 + c8] = v;
    __syncthreads();
    int ntl = t >> 6, L = t & 63;
    f16_8 w;
#pragma unroll
    for (int j = 0; j < 8; j++)
      w[j] = T[((L >> 4) * 8 + j) * 72 + ntl * 16 + (L & 15)];
    *(f16_8*)&w4p[((kt * 64 + nc * 4 + ntl) * 64 + L) * 8] = w;
  } else if (b < 264) {             // W2 pack
    int q0 = (b - 256) * 256 + t;
    int L = q0 & 63, nt = (q0 >> 6) & 7, kt = q0 >> 9;
    f16_8 v;
#pragma unroll
    for (int j = 0; j < 8; j++)
      v[j] = (_Float16)W2[(kt * 32 + ((L >> 4) << 3) + j) * 128 + (nt << 4) + (L & 15)];
    *(f16_8*)&w2p[((kt * 8 + nt) * 64 + L) * 8] = v;
  } else {                          // GN quadform consts
    if (t < 128) {
      float a0 = W1[t], a1 = W1[128 + t], a2 = W1[256 + t], bb = b1[t];
      float p[14] = {a0, a1, a2, bb,
                     a0 * a0, 2.f * a0 * a1, 2.f * a0 * a2,
                     a1 * a1, 2.f * a1 * a2, a2 * a2,
                     2.f * bb * a0, 2.f * bb * a1, 2.f * bb * a2, bb * bb};
#pragma unroll
      for (int m = 1; m < 16; m <<= 1)
#pragma unroll
        for (int k = 0; k < 14; k++) p[k] += __shfl_xor(p[k], m, 64);
      if ((t & 15) == 0) {
        int gg = t >> 4;
#pragma unroll
        for (int k = 0; k < 4; k++) gc[gg * 16 + k] = p[k] * 0.0625f;
#pragma unroll
        for (int k = 4; k < 14; k++) gc[gg * 16 + k] = p[k];
      }
    }
  }
}

// K1: per-graph node net + max pool; quadform stats (half2), octet fill,
// fp16 MFMA. LDS 40.2 KB -> 4 blocks/CU.
__global__ __launch_bounds__(256, 4) void k1_nodenet(
    const float* __restrict__ x, const float* __restrict__ roi,
    const float* __restrict__ W1, const float* __restrict__ b1,
    const float* __restrict__ gn_g, const float* __restrict__ gn_b,
    const _Float16* __restrict__ w2p, const float* __restrict__ b2,
    const float* __restrict__ gc, float* __restrict__ z) {
  __shared__ float4 xs4[NNODES];
  __shared__ f16_2 st[904];           // (inv, -mu*inv) per (n,g), packed half2
  __shared__ _Float16 A[128 * 136];   // pitch 136 fp16 = 272 B
  int t = threadIdx.x, g = blockIdx.x;
  int lane = t & 63, wv = t >> 6, quad = lane >> 4, l16 = lane & 15;

  int gs = t & 7;
  float gcv[14];
#pragma unroll
  for (int j = 0; j < 14; j++) gcv[j] = gc[gs * 16 + j];

  int o = t & 15;
  float pw0[8], pw1[8], pw2[8], pb[8], pg[8], pbe[8];
#pragma unroll
  for (int j = 0; j < 8; j++) {
    int c = o * 8 + j;
    pw0[j] = W1[c]; pw1[j] = W1[128 + c]; pw2[j] = W1[256 + c];
    pb[j] = b1[c];  pg[j] = gn_g[c];      pbe[j] = gn_b[c];
  }

  f16_8 bh[4][2];
#pragma unroll
  for (int kt = 0; kt < 4; kt++)
#pragma unroll
    for (int ni = 0; ni < 2; ni++)
      bh[kt][ni] = *(const f16_8*)&w2p[((kt * 8 + wv * 2 + ni) * 64 + lane) * 8];

  for (int i = t; i < NNODES * 3; i += 256) {
    float v = x[g * (NNODES * 3) + i] * roi[i];
    ((float*)xs4)[(i / 3) * 4 + (i % 3)] = v;
  }
  __syncthreads();

  for (int it = t; it < 904; it += 256) {
    int n = it >> 3;
    float4 xv = xs4[n];
    float mu = fmaf(xv.z, gcv[2], fmaf(xv.y, gcv[1], fmaf(xv.x, gcv[0], gcv[3])));
    float qf = fmaf(xv.z, gcv[12], fmaf(xv.y, gcv[11], fmaf(xv.x, gcv[10], gcv[13])));
    float u0 = fmaf(xv.z, gcv[6], fmaf(xv.y, gcv[5], xv.x * gcv[4]));
    qf = fmaf(xv.x, u0, qf);
    float u1 = fmaf(xv.z, gcv[8], xv.y * gcv[7]);
    qf = fmaf(xv.y, u1, qf);
    qf = fmaf(xv.z * xv.z, gcv[9], qf);
    float var = fmaxf(qf * 0.0625f - mu * mu, 0.0f);
    float inv = rsqrtf(var + 1e-5f);
    f16_2 s2 = {(_Float16)inv, (_Float16)(-mu * inv)};
    st[it] = s2;
  }
  __syncthreads();

  for (int it = t; it < 2048; it += 256) {
    int n = it >> 4;
    f16_8 hv;
    if (n < NNODES) {
      float4 xv = xs4[n];
      f16_2 s2 = st[n * 8 + (o >> 1)];
      float ia = (float)s2[0], ib = (float)s2[1];
#pragma unroll
      for (int j = 0; j < 8; j++) {
        float h = fmaf(xv.z, pw2[j], fmaf(xv.y, pw1[j], fmaf(xv.x, pw0[j], pb[j])));
        float y = fmaf(fmaf(h, ia, ib), pg[j], pbe[j]);
        y = (y > 0.0f) ? y : 0.2f * y;
        hv[j] = (_Float16)y;
      }
    } else {
#pragma unroll
      for (int j = 0; j < 8; j++) hv[j] = (_Float16)0.f;
    }
    *(f16_8*)&A[n * 136 + o * 8] = hv;
  }
  __syncthreads();

  f32x4 acc[2][8];
#pragma unroll
  for (int a = 0; a < 2; a++)
#pragma unroll
    for (int m = 0; m < 8; m++) acc[a][m] = (f32x4){0.f, 0.f, 0.f, 0.f};

#pragma unroll
  for (int kt = 0; kt < 4; kt++) {
    f16_8 ah[8];
#pragma unroll
    for (int mt = 0; mt < 8; mt++)
      ah[mt] = *(const f16_8*)&A[(mt * 16 + l16) * 136 + kt * 32 + quad * 8];
#pragma unroll
    for (int ni = 0; ni < 2; ni++)
#pragma unroll
      for (int mt = 0; mt < 8; mt++)
        acc[ni][mt] = __builtin_amdgcn_mfma_f32_16x16x32_f16(ah[mt], bh[kt][ni], acc[ni][mt], 0, 0, 0);
  }

#pragma unroll
  for (int ni = 0; ni < 2; ni++) {
    int nt = wv * 2 + ni;
    float m = -3.4e38f;
#pragma unroll
    for (int mt = 0; mt < 8; mt++)
#pragma unroll
      for (int r = 0; r < 4; r++) {
        int row = mt * 16 + quad * 4 + r;
        if (row < NNODES) m = fmaxf(m, acc[ni][mt][r]);
      }
    m = fmaxf(m, __shfl_xor(m, 16, 64));
    m = fmaxf(m, __shfl_xor(m, 32, 64));
    if (quad == 0) {
      int col = nt * 16 + l16;
      z[g * 128 + col] = m + b2[col];
    }
  }
}

// K2: p = z @ W3 + b3 fp32; 1024 blocks (rb256 x cb4), 16 rows x 128 cols,
// 4 blocks/CU. Thread: 2 rows x 4 cols.
__global__ __launch_bounds__(256) void k2_proj(
    const float* __restrict__ z, const float* __restrict__ W3,
    const float* __restrict__ b3, float* __restrict__ p) {
  __shared__ float zs[16 * 128];
  int t = threadIdx.x;
  int rb = blockIdx.x >> 2, cbb = blockIdx.x & 3;
  int gr0 = rb * 16, cc0 = cbb * 128;
  for (int i = t; i < 2048; i += 256) zs[i] = z[gr0 * 128 + i];
  int cg = t & 31, rg = t >> 5;
  int cc = cc0 + cg * 4;
  float4 bb = *(const float4*)&b3[cc];
  float acc0[4] = {0.f, 0.f, 0.f, 0.f}, acc1[4] = {0.f, 0.f, 0.f, 0.f};
  __syncthreads();

#pragma unroll 8
  for (int k = 0; k < 128; k++) {
    float4 w = *(const float4*)&W3[k * 512 + cc];
    float z0 = zs[rg * 256 + k];
    float z1 = zs[rg * 256 + 128 + k];
    acc0[0] = fmaf(z0, w.x, acc0[0]); acc0[1] = fmaf(z0, w.y, acc0[1]);
    acc0[2] = fmaf(z0, w.z, acc0[2]); acc0[3] = fmaf(z0, w.w, acc0[3]);
    acc1[0] = fmaf(z1, w.x, acc1[0]); acc1[1] = fmaf(z1, w.y, acc1[1]);
    acc1[2] = fmaf(z1, w.z, acc1[2]); acc1[3] = fmaf(z1, w.w, acc1[3]);
  }
  int r0 = gr0 + rg * 2;
  float4 o0 = make_float4(acc0[0] + bb.x, acc0[1] + bb.y, acc0[2] + bb.z, acc0[3] + bb.w);
  float4 o1 = make_float4(acc1[0] + bb.x, acc1[1] + bb.y, acc1[2] + bb.z, acc1[3] + bb.w);
  *(float4*)&p[r0 * 512 + cc] = o0;
  *(float4*)&p[(r0 + 1) * 512 + cc] = o1;
}

// K2b/K3: deterministic BN stats (fixed-order partials, no atomics)
__global__ __launch_bounds__(256) void k2b_partial(
    const float* __restrict__ p, float* __restrict__ psum, float* __restrict__ psq) {
  int t = threadIdx.x, b = blockIdx.x;
  int r0 = b * 128;
  float s0 = 0.f, q0 = 0.f, s1 = 0.f, q1 = 0.f;
  for (int r = 0; r < 128; r++) {
    float v0 = p[(r0 + r) * 512 + t];
    float v1 = p[(r0 + r) * 512 + t + 256];
    s0 += v0; q0 = fmaf(v0, v0, q0);
    s1 += v1; q1 = fmaf(v1, v1, q1);
  }
  psum[b * 512 + t] = s0;
  psum[b * 512 + t + 256] = s1;
  psq[b * 512 + t] = q0;
  psq[b * 512 + t + 256] = q1;
}

__global__ __launch_bounds__(512) void k3_stats(
    const float* __restrict__ psum, const float* __restrict__ psq,
    const float* __restrict__ bn_g, const float* __restrict__ bn_b,
    float* __restrict__ sa, float* __restrict__ sd) {
  int c = threadIdx.x;
  float s = 0.f, q = 0.f;
#pragma unroll 4
  for (int b = 0; b < 32; b++) {
    s += psum[b * 512 + c];
    q += psq[b * 512 + c];
  }
  float mu = s * (1.0f / 4096.0f);
  float var = fmaxf(q * (1.0f / 4096.0f) - mu * mu, 0.0f);
  float sc = bn_g[c] * rsqrtf(var + 1e-5f);
  sa[c] = sc;
  sd[c] = bn_b[c] - mu * sc;
}

// K4a: 512 blocks (rb64 x cb8), 64 rows x 128 cols. Double-buffered T,
// ONE barrier per kt, prefetch one kt ahead. ~15 KB LDS -> ~5 blocks/CU.
__global__ __launch_bounds__(256) void k4a_gemm(
    const float* __restrict__ p, const float* __restrict__ sa,
    const float* __restrict__ sd, const _Float16* __restrict__ w4p,
    const float* __restrict__ b4, float* __restrict__ out,
    float* __restrict__ psn) {
  __shared__ _Float16 T[2][64 * 40];
  __shared__ float sas[512], sds[512];
  __shared__ float rred[4 * 64];
  int t = threadIdx.x;
  int rb = blockIdx.x & 63, cb = blockIdx.x >> 6;
  int lane = t & 63, wv = t >> 6, quad = lane >> 4, l16 = lane & 15;

  for (int i = t; i < 512; i += 256) { sas[i] = sa[i]; sds[i] = sd[i]; }

  int srow = t >> 2, sc8 = (t & 3) * 8;
  const float* prow = &p[(rb * 64 + srow) * 512];
  float4 pa0 = *(const float4*)&prow[sc8];
  float4 pa1 = *(const float4*)&prow[sc8 + 4];
  f16_8 bfr[2];
#pragma unroll
  for (int ni = 0; ni < 2; ni++)
    bfr[ni] = *(const f16_8*)&w4p[((cb * 8 + wv * 2 + ni) * 64 + lane) * 8];
  __syncthreads();   // sas/sds ready

  {
    f16_8 v;
#pragma unroll
    for (int j = 0; j < 4; j++)
      v[j] = (_Float16)fmaxf(fmaf(((float*)&pa0)[j], sas[sc8 + j], sds[sc8 + j]), 0.0f);
#pragma unroll
    for (int j = 0; j < 4; j++)
      v[4 + j] = (_Float16)fmaxf(fmaf(((float*)&pa1)[j], sas[sc8 + 4 + j], sds[sc8 + 4 + j]), 0.0f);
    *(f16_8*)&T[0][srow * 40 + sc8] = v;
  }
  __syncthreads();   // T[0] ready

  f32x4 acc[2][4];
#pragma unroll
  for (int a = 0; a < 2; a++)
#pragma unroll
    for (int m = 0; m < 4; m++) acc[a][m] = (f32x4){0.f, 0.f, 0.f, 0.f};

  for (int kt = 0; kt < 16; kt++) {
    int nb = kt + 1;
    float4 na0, na1;
    if (nb < 16) {
      na0 = *(const float4*)&prow[nb * 32 + sc8];
      na1 = *(const float4*)&prow[nb * 32 + sc8 + 4];
    }
    f16_8 bc0 = bfr[0], bc1 = bfr[1];
    if (nb < 16) {
#pragma unroll
      for (int ni = 0; ni < 2; ni++)
        bfr[ni] = *(const f16_8*)&w4p[((nb * 64 + cb * 8 + wv * 2 + ni) * 64 + lane) * 8];
    }
    const _Float16* Tb = &T[kt & 1][0];
#pragma unroll
    for (int mt = 0; mt < 4; mt++) {
      f16_8 af = *(const f16_8*)&Tb[(mt * 16 + l16) * 40 + quad * 8];
      acc[0][mt] = __builtin_amdgcn_mfma_f32_16x16x32_f16(af, bc0, acc[0][mt], 0, 0, 0);
      acc[1][mt] = __builtin_amdgcn_mfma_f32_16x16x32_f16(af, bc1, acc[1][mt], 0, 0, 0);
    }
    if (nb < 16) {
      int kc = nb * 32 + sc8;
      f16_8 v;
#pragma unroll
      for (int j = 0; j < 4; j++)
        v[j] = (_Float16)fmaxf(fmaf(((float*)&na0)[j], sas[kc + j], sds[kc + j]), 0.0f);
#pragma unroll
      for (int j = 0; j < 4; j++)
        v[4 + j] = (_Float16)fmaxf(fmaf(((float*)&na1)[j], sas[kc + 4 + j], sds[kc + 4 + j]), 0.0f);
      *(f16_8*)&T[nb & 1][srow * 40 + sc8] = v;
    }
    __syncthreads();   // single barrier/kt: write(nb)->MFMA(nb), read(kt)->write(kt+1)
  }

  // epilogue: +b4, unnormalized store, row sumsq partials
  float rsq[4][4];
#pragma unroll
  for (int mt = 0; mt < 4; mt++)
#pragma unroll
    for (int r = 0; r < 4; r++) rsq[mt][r] = 0.0f;
#pragma unroll
  for (int ni = 0; ni < 2; ni++) {
    int col = cb * 128 + (wv * 2 + ni) * 16 + l16;
    float bv = b4[col];
#pragma unroll
    for (int mt = 0; mt < 4; mt++)
#pragma unroll
      for (int r = 0; r < 4; r++) {
        float v = acc[ni][mt][r] + bv;
        out[(rb * 64 + mt * 16 + quad * 4 + r) * 1024 + col] = v;
        rsq[mt][r] = fmaf(v, v, rsq[mt][r]);
      }
  }
#pragma unroll
  for (int m = 1; m < 16; m <<= 1)
#pragma unroll
    for (int mt = 0; mt < 4; mt++)
#pragma unroll
      for (int r = 0; r < 4; r++) rsq[mt][r] += __shfl_xor(rsq[mt][r], m, 64);
  if (l16 == 0) {
#pragma unroll
    for (int mt = 0; mt < 4; mt++)
#pragma unroll
      for (int r = 0; r < 4; r++)
        rred[wv * 64 + mt * 16 + quad * 4 + r] = rsq[mt][r];
  }
  __syncthreads();
  if (t < 64) {
    float s = rred[t] + rred[64 + t] + rred[128 + t] + rred[192 + t];
    psn[cb * 4096 + rb * 64 + t] = s;
  }
}

// K4b: in-place L2 normalize of out, 4 rows/block.
__global__ __launch_bounds__(256) void k4b_norm(
    float* __restrict__ out, const float* __restrict__ psn) {
  int t = threadIdx.x;
  int row = blockIdx.x * 4 + (t >> 6);
  float s = 0.f;
#pragma unroll
  for (int cb = 0; cb < 8; cb++) s += psn[cb * 4096 + row];
  float inv = 1.0f / fmaxf(sqrtf(s), 1e-12f);
  int c0 = (t & 63) * 4;
#pragma unroll
  for (int it = 0; it < 4; it++) {
    float4 v = *(const float4*)&out[row * 1024 + it * 256 + c0];
    v.x *= inv; v.y *= inv; v.z *= inv; v.w *= inv;
    *(float4*)&out[row * 1024 + it * 256 + c0] = v;
  }
}

extern "C" void kernel_launch(void* const* d_in, const int* in_sizes, int n_in,
                              void* d_out, int out_size, void* d_ws, size_t ws_size,
                              hipStream_t stream) {
  const float* x   = (const float*)d_in[0];
  const float* roi = (const float*)d_in[1];
  const float* W1  = (const float*)d_in[2];
  const float* b1  = (const float*)d_in[3];
  const float* gng = (const float*)d_in[4];
  const float* gnb = (const float*)d_in[5];
  const float* W2  = (const float*)d_in[6];
  const float* b2  = (const float*)d_in[7];
  const float* W3  = (const float*)d_in[8];
  const float* b3  = (const float*)d_in[9];
  const float* bng = (const float*)d_in[10];
  const float* bnb = (const float*)d_in[11];
  const float* W4  = (const float*)d_in[12];
  const float* b4  = (const float*)d_in[13];
  float* out = (float*)d_out;

  char* ws = (char*)d_ws;
  float*    z    = (float*)(ws + Z_OFF);
  float*    psum = (float*)(ws + PSUM_OFF);
  float*    psq  = (float*)(ws + PSQ_OFF);
  float*    psn  = (float*)(ws + PSN_OFF);
  float*    p    = (float*)(ws + P_OFF);
  float*    gc   = (float*)(ws + GC_OFF);
  float*    sa   = (float*)(ws + SA_OFF);
  float*    sd   = (float*)(ws + SD_OFF);
  _Float16* w2p  = (_Float16*)(ws + W2P_OFF);
  _Float16* w4p  = (_Float16*)(ws + W4P_OFF);

  k0_prep<<<265, 256, 0, stream>>>(W2, W4, W1, b1, w2p, w4p, gc);
  k1_nodenet<<<NGRAPH, 256, 0, stream>>>(x, roi, W1, b1, gng, gnb, w2p, b2, gc, z);
  k2_proj<<<1024, 256, 0, stream>>>(z, W3, b3, p);
  k2b_partial<<<32, 256, 0, stream>>>(p, psum, psq);
  k3_stats<<<1, 512, 0, stream>>>(psum, psq, bng, bnb, sa, sd);
  k4a_gemm<<<512, 256, 0, stream>>>(p, sa, sd, w4p, b4, out, psn);
  k4b_norm<<<1024, 256, 0, stream>>>(out, psn);
}